// Round 1
// baseline (875.549 us; speedup 1.0000x reference)
//
#include <hip/hip_runtime.h>
#include <hip/hip_bf16.h>

// GCN actor-critic: 3x (segment_sum(h[src], dst) -> Linear+ReLU), then
// mean-node head (v, pi_done) and per-node head (pi_graph).
// N=50000 nodes, E=1.6M edges, dims fixed at 128.
//
// Plan: build CSR by dst once per call (hist -> scan -> scatter), then each
// layer = gather-sum aggregate (no float atomics) + f32 tiled GEMM (LDS).

#define HID 128

// ---------------------------------------------------------------- utilities
__global__ void zero_int_kernel(int* __restrict__ p, int n) {
    int i = blockIdx.x * blockDim.x + threadIdx.x;
    if (i < n) p[i] = 0;
}

__global__ void hist_kernel(const int* __restrict__ dst, int* __restrict__ deg, int ne) {
    int e = blockIdx.x * blockDim.x + threadIdx.x;
    if (e < ne) atomicAdd(&deg[dst[e]], 1);
}

// exclusive scan of deg[0..n) -> row_ptr[0..n], cursor[i] = row_ptr[i]
__global__ __launch_bounds__(1024) void scan_kernel(const int* __restrict__ deg,
                                                    int* __restrict__ row_ptr,
                                                    int* __restrict__ cursor, int n) {
    __shared__ int sh[1024];
    int carry = 0;
    if (threadIdx.x == 0) row_ptr[0] = 0;
    for (int base = 0; base < n; base += 1024) {
        int i = base + (int)threadIdx.x;
        int v = (i < n) ? deg[i] : 0;
        sh[threadIdx.x] = v;
        __syncthreads();
        // Hillis-Steele inclusive scan
        for (int off = 1; off < 1024; off <<= 1) {
            int mine = sh[threadIdx.x];
            int add = (threadIdx.x >= (unsigned)off) ? sh[threadIdx.x - off] : 0;
            __syncthreads();
            sh[threadIdx.x] = mine + add;
            __syncthreads();
        }
        int incl = sh[threadIdx.x];
        if (i < n) {
            row_ptr[i + 1] = carry + incl;
            cursor[i] = carry + incl - v;
        }
        carry += sh[1023];
        __syncthreads();
    }
}

__global__ void scatter_kernel(const int* __restrict__ src, const int* __restrict__ dst,
                               int* __restrict__ cursor, int* __restrict__ eidx, int ne) {
    int e = blockIdx.x * blockDim.x + threadIdx.x;
    if (e < ne) {
        int d = dst[e];
        int pos = atomicAdd(&cursor[d], 1);
        eidx[pos] = src[e];
    }
}

// ------------------------------------------------------------- aggregation
// one 32-lane group per node; each lane owns one float4 (4 of 128 dims)
__global__ __launch_bounds__(256) void aggregate_kernel(
        const float4* __restrict__ x, const int* __restrict__ row_ptr,
        const int* __restrict__ eidx, float4* __restrict__ agg, int n) {
    int g = (int)((blockIdx.x * blockDim.x + threadIdx.x) >> 5);
    int lane = threadIdx.x & 31;
    if (g >= n) return;
    int beg = row_ptr[g], end = row_ptr[g + 1];
    float4 acc = make_float4(0.f, 0.f, 0.f, 0.f);
    for (int e = beg; e < end; ++e) {
        int s = eidx[e];
        float4 v = x[(size_t)s * 32 + lane];
        acc.x += v.x; acc.y += v.y; acc.z += v.z; acc.w += v.w;
    }
    agg[(size_t)g * 32 + lane] = acc;
}

// ---------------------------------------------------------------- GEMM f32
// out[M,128] = relu(A[M,128] @ W[128,128] + b). Block: 64 rows x 64 cols
// (blockIdx.y picks col half). 256 threads, 4x4 register tile per thread.
__global__ __launch_bounds__(256) void gemm_relu_kernel(
        const float* __restrict__ A, const float* __restrict__ W,
        const float* __restrict__ bias, float* __restrict__ out, int M) {
    __shared__ float Ash[64][132];   // +4 pad -> A-column reads are 2-way (free)
    __shared__ float Wsh[128][64];
    const int row0 = blockIdx.x * 64;
    const int nh = blockIdx.y * 64;
    const int t = threadIdx.x;

    // load A tile (64 x 128) as 2048 float4
    #pragma unroll
    for (int j = 0; j < 8; ++j) {
        int idx = t + 256 * j;
        int r = idx >> 5, c4 = idx & 31;
        float4 v = make_float4(0.f, 0.f, 0.f, 0.f);
        if (row0 + r < M) v = ((const float4*)A)[(size_t)(row0 + r) * 32 + c4];
        *(float4*)&Ash[r][c4 * 4] = v;
    }
    // load W tile (128 x 64) as 2048 float4
    #pragma unroll
    for (int j = 0; j < 8; ++j) {
        int idx = t + 256 * j;
        int r = idx >> 4, c4 = idx & 15;
        float4 v = ((const float4*)W)[(size_t)r * 32 + (nh >> 2) + c4];
        *(float4*)&Wsh[r][c4 * 4] = v;
    }
    __syncthreads();

    const int cg = t & 15, rg = t >> 4;
    const int c0 = cg * 4, r0 = rg * 4;
    float acc[4][4] = {};
    #pragma unroll 4
    for (int k = 0; k < 128; ++k) {
        float4 wv = *(const float4*)&Wsh[k][c0];
        float a0 = Ash[r0 + 0][k];
        float a1 = Ash[r0 + 1][k];
        float a2 = Ash[r0 + 2][k];
        float a3 = Ash[r0 + 3][k];
        acc[0][0] += a0 * wv.x; acc[0][1] += a0 * wv.y; acc[0][2] += a0 * wv.z; acc[0][3] += a0 * wv.w;
        acc[1][0] += a1 * wv.x; acc[1][1] += a1 * wv.y; acc[1][2] += a1 * wv.z; acc[1][3] += a1 * wv.w;
        acc[2][0] += a2 * wv.x; acc[2][1] += a2 * wv.y; acc[2][2] += a2 * wv.z; acc[2][3] += a2 * wv.w;
        acc[3][0] += a3 * wv.x; acc[3][1] += a3 * wv.y; acc[3][2] += a3 * wv.z; acc[3][3] += a3 * wv.w;
    }

    float4 bv = *(const float4*)&bias[nh + c0];
    #pragma unroll
    for (int i = 0; i < 4; ++i) {
        int r = row0 + r0 + i;
        if (r < M) {
            float4 o;
            o.x = fmaxf(acc[i][0] + bv.x, 0.f);
            o.y = fmaxf(acc[i][1] + bv.y, 0.f);
            o.z = fmaxf(acc[i][2] + bv.z, 0.f);
            o.w = fmaxf(acc[i][3] + bv.w, 0.f);
            ((float4*)out)[(size_t)r * 32 + ((nh + c0) >> 2)] = o;
        }
    }
}

// ---------------------------------------------------------------- heads
// partial column sums: grid of 128 blocks x 128 threads (deterministic)
__global__ __launch_bounds__(128) void colsum_part_kernel(
        const float* __restrict__ h, float* __restrict__ part, int n) {
    int d = threadIdx.x;
    float acc = 0.f;
    for (int r = blockIdx.x; r < n; r += gridDim.x)
        acc += h[(size_t)r * 128 + d];
    part[blockIdx.x * 128 + d] = acc;
}

__global__ __launch_bounds__(128) void head_final_kernel(
        const float* __restrict__ part, int nparts,
        const float* __restrict__ w_v, const float* __restrict__ b_v,
        const float* __restrict__ w_pd, const float* __restrict__ b_pd,
        float* __restrict__ out, int n_nodes) {
    __shared__ float sv[128], sd[128];
    int d = threadIdx.x;
    float s = 0.f;
    for (int i = 0; i < nparts; ++i) s += part[i * 128 + d];
    float m = s / (float)n_nodes;
    sv[d] = m * w_v[d];
    sd[d] = m * w_pd[d];
    __syncthreads();
    for (int off = 64; off > 0; off >>= 1) {
        if (d < off) { sv[d] += sv[d + off]; sd[d] += sd[d + off]; }
        __syncthreads();
    }
    if (d == 0) {
        out[n_nodes] = sd[0] + b_pd[0];       // pi_done at index N
        out[n_nodes + 1] = sv[0] + b_v[0];    // v at index N+1
    }
}

// pi_graph: one 64-lane wave per node
__global__ __launch_bounds__(256) void pig_kernel(
        const float* __restrict__ h, const float* __restrict__ w_pg,
        const float* __restrict__ b_pg, float* __restrict__ out, int n) {
    int g = (int)((blockIdx.x * blockDim.x + threadIdx.x) >> 6);
    int l = threadIdx.x & 63;
    if (g >= n) return;
    float acc = h[(size_t)g * 128 + l] * w_pg[l] +
                h[(size_t)g * 128 + 64 + l] * w_pg[64 + l];
    #pragma unroll
    for (int off = 32; off > 0; off >>= 1) acc += __shfl_xor(acc, off);
    if (l == 0) out[g] = acc + b_pg[0];
}

// ---------------------------------------------------------------- launcher
static inline size_t align_up(size_t v, size_t a) { return (v + a - 1) & ~(a - 1); }

extern "C" void kernel_launch(void* const* d_in, const int* in_sizes, int n_in,
                              void* d_out, int out_size, void* d_ws, size_t ws_size,
                              hipStream_t stream) {
    const float* x    = (const float*)d_in[0];
    const int*   src  = (const int*)d_in[1];
    const int*   dst  = (const int*)d_in[2];
    const float* W0   = (const float*)d_in[3];
    const float* b0   = (const float*)d_in[4];
    const float* W1   = (const float*)d_in[5];
    const float* b1   = (const float*)d_in[6];
    const float* W2   = (const float*)d_in[7];
    const float* b2   = (const float*)d_in[8];
    const float* w_pg = (const float*)d_in[9];
    const float* b_pg = (const float*)d_in[10];
    const float* w_pd = (const float*)d_in[11];
    const float* b_pd = (const float*)d_in[12];
    const float* w_v  = (const float*)d_in[13];
    const float* b_v  = (const float*)d_in[14];
    float* out = (float*)d_out;

    const int NN = in_sizes[0] / HID;   // 50000
    const int NE = in_sizes[1];         // 1600000

    // workspace carve-up
    char* w = (char*)d_ws;
    int* deg     = (int*)w;  w += align_up((size_t)NN * 4, 256);
    int* row_ptr = (int*)w;  w += align_up((size_t)(NN + 1) * 4, 256);
    int* cursor  = (int*)w;  w += align_up((size_t)NN * 4, 256);
    int* eidx    = (int*)w;  w += align_up((size_t)NE * 4, 256);
    float* agg   = (float*)w; w += align_up((size_t)NN * HID * 4, 256);
    float* h     = (float*)w; w += align_up((size_t)NN * HID * 4, 256);
    float* part  = (float*)w; w += align_up((size_t)128 * 128 * 4, 256);
    (void)ws_size; (void)n_in; (void)out_size;

    // ---- build CSR by dst (reused for all 3 layers)
    zero_int_kernel<<<(NN + 255) / 256, 256, 0, stream>>>(deg, NN);
    hist_kernel<<<(NE + 255) / 256, 256, 0, stream>>>(dst, deg, NE);
    scan_kernel<<<1, 1024, 0, stream>>>(deg, row_ptr, cursor, NN);
    scatter_kernel<<<(NE + 255) / 256, 256, 0, stream>>>(src, dst, cursor, eidx, NE);

    const int agg_blocks = (NN * 32 + 255) / 256;
    dim3 gemm_grid((NN + 63) / 64, 2);

    // ---- layer 1
    aggregate_kernel<<<agg_blocks, 256, 0, stream>>>((const float4*)x, row_ptr, eidx,
                                                     (float4*)agg, NN);
    gemm_relu_kernel<<<gemm_grid, 256, 0, stream>>>(agg, W0, b0, h, NN);
    // ---- layer 2
    aggregate_kernel<<<agg_blocks, 256, 0, stream>>>((const float4*)h, row_ptr, eidx,
                                                     (float4*)agg, NN);
    gemm_relu_kernel<<<gemm_grid, 256, 0, stream>>>(agg, W1, b1, h, NN);
    // ---- layer 3
    aggregate_kernel<<<agg_blocks, 256, 0, stream>>>((const float4*)h, row_ptr, eidx,
                                                     (float4*)agg, NN);
    gemm_relu_kernel<<<gemm_grid, 256, 0, stream>>>(agg, W2, b2, h, NN);

    // ---- heads
    colsum_part_kernel<<<128, 128, 0, stream>>>(h, part, NN);
    head_final_kernel<<<1, 128, 0, stream>>>(part, 128, w_v, b_v, w_pd, b_pd, out, NN);
    pig_kernel<<<(NN * 64 + 255) / 256, 256, 0, stream>>>(h, w_pg, b_pg, out, NN);
}